// Round 1
// baseline (2323.085 us; speedup 1.0000x reference)
//
#include <hip/hip_runtime.h>
#include <hip/hip_bf16.h>

constexpr int HDIM = 8;
constexpr int EDIM = 8;

// h = x @ node_W + node_b   [N,8]@[8,64]
__global__ void init_h_kernel(const float* __restrict__ x, const float* __restrict__ W,
                              const float* __restrict__ b, float* __restrict__ h, int n) {
  int gid = blockIdx.x * 256 + threadIdx.x;
  if (gid >= n * 64) return;
  int row = gid >> 6, c = gid & 63;
  const float* xr = x + (size_t)row * HDIM;
  float acc = b[c];
#pragma unroll
  for (int k = 0; k < HDIM; ++k) acc = fmaf(xr[k], W[k * 64 + c], acc);
  h[gid] = acc;
}

__global__ void deg_kernel(const int* __restrict__ dst, int* __restrict__ deg, int E) {
  int e = blockIdx.x * 256 + threadIdx.x;
  if (e < E) atomicAdd(&deg[dst[e]], 1);
}

// single-block exclusive scan over deg[0..n) -> rowstart, fillptr; rowstart[n] = total
__global__ void scan_kernel(const int* __restrict__ deg, int* __restrict__ rowstart,
                            int* __restrict__ fillptr, int n, int total) {
  __shared__ int part[1024];
  int tid = threadIdx.x;
  int chunk = (n + 1023) >> 10;
  int lo = tid * chunk, hi = min(n, lo + chunk);
  int s = 0;
  for (int i = lo; i < hi; ++i) s += deg[i];
  part[tid] = s;
  __syncthreads();
  for (int offd = 1; offd < 1024; offd <<= 1) {
    int add = (tid >= offd) ? part[tid - offd] : 0;
    __syncthreads();
    part[tid] += add;
    __syncthreads();
  }
  int run = (tid == 0) ? 0 : part[tid - 1];
  for (int i = lo; i < hi; ++i) {
    rowstart[i] = run; fillptr[i] = run;
    run += deg[i];
  }
  if (tid == 1023) rowstart[n] = total;
}

// scatter edges into CSR slots; also reorder edge_attr rows into CSR order
__global__ void fill_kernel(const int* __restrict__ src, const int* __restrict__ dst,
                            const float* __restrict__ edge_attr, int* __restrict__ fillptr,
                            int* __restrict__ csr_src, float* __restrict__ ea_csr, int E) {
  int e = blockIdx.x * 256 + threadIdx.x;
  if (e >= E) return;
  int d = dst[e];
  int slot = atomicAdd(&fillptr[d], 1);
  csr_src[slot] = src[e];
  const float4* ap = (const float4*)(edge_attr + (size_t)e * EDIM);
  float4* op = (float4*)(ea_csr + (size_t)slot * EDIM);
  op[0] = ap[0];
  op[1] = ap[1];
}

// per-channel sums and sumsqs of h over all nodes
__global__ void bn_stats_kernel(const float* __restrict__ h, float* __restrict__ sums, int n) {
  int lane = threadIdx.x & 63, wid = threadIdx.x >> 6;
  int w = blockIdx.x * 4 + wid, nw = gridDim.x * 4;
  float s = 0.f, q = 0.f;
  for (int r = w; r < n; r += nw) {
    float v = h[(size_t)r * 64 + lane];
    s += v; q = fmaf(v, v, q);
  }
  atomicAdd(&sums[lane], s);
  atomicAdd(&sums[64 + lane], q);
}

// hn = relu(BN(h))
__global__ void normalize_kernel(const float* __restrict__ h, const float* __restrict__ sums,
                                 const float* __restrict__ g, const float* __restrict__ b,
                                 float* __restrict__ hn, int n, float invN) {
  int gid = blockIdx.x * 256 + threadIdx.x;
  if (gid >= n * 64) return;
  int c = gid & 63;
  float mu = sums[c] * invN;
  float var = sums[64 + c] * invN - mu * mu;
  float rstd = rsqrtf(var + 1e-5f);
  float v = (h[gid] - mu) * rstd * g[c] + b[c];
  hn[gid] = fmaxf(v, 0.f);
}

// one wave per dst node; lane = channel. out = softmax-agg + hn
__global__ void aggregate_kernel(const float* __restrict__ hn, const int* __restrict__ rowstart,
                                 const int* __restrict__ csr_src, const float* __restrict__ ea_csr,
                                 const float* __restrict__ edge_W, const float* __restrict__ edge_b,
                                 const float* __restrict__ t, float* __restrict__ out, int n) {
  int lane = threadIdx.x & 63;
  int node = blockIdx.x * 4 + (threadIdx.x >> 6);
  if (node >= n) return;
  float wcol[EDIM];
#pragma unroll
  for (int k = 0; k < EDIM; ++k) wcol[k] = edge_W[k * 64 + lane];
  float eb = edge_b[lane];
  float tt = t[0];
  int s0 = __builtin_amdgcn_readfirstlane(rowstart[node]);
  int s1 = __builtin_amdgcn_readfirstlane(rowstart[node + 1]);
  float hd = hn[(size_t)node * 64 + lane];
  float den = 0.f, num = 0.f;
  for (int j = s0; j < s1; ++j) {
    int s = __builtin_amdgcn_readfirstlane(csr_src[j]);
    const float* ea = ea_csr + (size_t)j * EDIM;
    float hv = hn[(size_t)s * 64 + lane];
    float ev = eb;
#pragma unroll
    for (int k = 0; k < EDIM; ++k) ev = fmaf(ea[k], wcol[k], ev);
    float msg = fmaxf(hv + ev, 0.f) + 1e-7f;
    float p = __expf(msg * tt);
    den += p;
    num = fmaf(p, msg, num);
  }
  out[(size_t)node * 64 + lane] = num / fmaxf(den, 1e-16f) + hd;
}

// fused MLP: y=relu(LN(out@W1+b1)); h_out = h_in + y@W2 + b2. wave handles 4 nodes.
__global__ __launch_bounds__(512) void mlp_kernel(
    const float* __restrict__ outv, const float* __restrict__ h_in,
    const float* __restrict__ W1, const float* __restrict__ b1,
    const float* __restrict__ lng, const float* __restrict__ lnb,
    const float* __restrict__ W2, const float* __restrict__ b2,
    float* __restrict__ h_out, int n) {
  __shared__ float W1s[64 * 128];
  __shared__ float W2s[128 * 64];
  __shared__ float zs[8][4][128];
  int tid = threadIdx.x;
  for (int i = tid; i < 8192; i += 512) { W1s[i] = W1[i]; W2s[i] = W2[i]; }
  __syncthreads();
  int lane = tid & 63, wid = tid >> 6;
  float b1a = b1[2 * lane], b1b = b1[2 * lane + 1];
  float ga = lng[2 * lane], gb = lng[2 * lane + 1];
  float la = lnb[2 * lane], lb = lnb[2 * lane + 1];
  float b2d = b2[lane];
  int ngroups = (n + 3) >> 2;
  for (int grp = blockIdx.x * 8 + wid; grp < ngroups; grp += gridDim.x * 8) {
    int node0 = grp * 4;
#pragma unroll
    for (int j = 0; j < 4; ++j) {
      int nd = node0 + j;
      float v = (nd < n) ? outv[(size_t)nd * 64 + lane] : 0.f;
      zs[wid][j][lane] = v;
    }
    float2 acc[4];
#pragma unroll
    for (int j = 0; j < 4; ++j) acc[j] = make_float2(b1a, b1b);
#pragma unroll
    for (int c4 = 0; c4 < 16; ++c4) {
      float4 o4[4];
#pragma unroll
      for (int j = 0; j < 4; ++j) o4[j] = *(const float4*)&zs[wid][j][c4 * 4];
#pragma unroll
      for (int kk = 0; kk < 4; ++kk) {
        int c = c4 * 4 + kk;
        float2 w = *(const float2*)&W1s[c * 128 + 2 * lane];
#pragma unroll
        for (int j = 0; j < 4; ++j) {
          float oc = kk == 0 ? o4[j].x : kk == 1 ? o4[j].y : kk == 2 ? o4[j].z : o4[j].w;
          acc[j].x = fmaf(oc, w.x, acc[j].x);
          acc[j].y = fmaf(oc, w.y, acc[j].y);
        }
      }
    }
#pragma unroll
    for (int j = 0; j < 4; ++j) {
      float sx = acc[j].x + acc[j].y;
      float sq = fmaf(acc[j].x, acc[j].x, acc[j].y * acc[j].y);
#pragma unroll
      for (int off = 1; off < 64; off <<= 1) {
        sx += __shfl_xor(sx, off, 64);
        sq += __shfl_xor(sq, off, 64);
      }
      float mu = sx * (1.f / 128.f);
      float var = sq * (1.f / 128.f) - mu * mu;
      float rstd = rsqrtf(var + 1e-5f);
      float z0 = fmaxf((acc[j].x - mu) * rstd * ga + la, 0.f);
      float z1 = fmaxf((acc[j].y - mu) * rstd * gb + lb, 0.f);
      *(float2*)&zs[wid][j][2 * lane] = make_float2(z0, z1);
    }
    float accd[4];
#pragma unroll
    for (int j = 0; j < 4; ++j) accd[j] = b2d;
#pragma unroll
    for (int h4 = 0; h4 < 32; ++h4) {
      float4 z4[4];
#pragma unroll
      for (int j = 0; j < 4; ++j) z4[j] = *(const float4*)&zs[wid][j][h4 * 4];
#pragma unroll
      for (int kk = 0; kk < 4; ++kk) {
        int hh = h4 * 4 + kk;
        float w = W2s[hh * 64 + lane];
#pragma unroll
        for (int j = 0; j < 4; ++j) {
          float zc = kk == 0 ? z4[j].x : kk == 1 ? z4[j].y : kk == 2 ? z4[j].z : z4[j].w;
          accd[j] = fmaf(zc, w, accd[j]);
        }
      }
    }
#pragma unroll
    for (int j = 0; j < 4; ++j) {
      int nd = node0 + j;
      if (nd < n) h_out[(size_t)nd * 64 + lane] = h_in[(size_t)nd * 64 + lane] + accd[j];
    }
  }
}

extern "C" void kernel_launch(void* const* d_in, const int* in_sizes, int n_in,
                              void* d_out, int out_size, void* d_ws, size_t ws_size,
                              hipStream_t stream) {
  const float* x = (const float*)d_in[0];
  const int* edge_index = (const int*)d_in[1];
  const float* edge_attr = (const float*)d_in[2];
  const float* node_W = (const float*)d_in[3];
  const float* node_b = (const float*)d_in[4];
  const float* edge_W = (const float*)d_in[5];
  const float* edge_b = (const float*)d_in[6];
  const float* bn_g = (const float*)d_in[7];
  const float* bn_b = (const float*)d_in[8];
  const float* t = (const float*)d_in[9];
  const float* W1 = (const float*)d_in[10];
  const float* b1 = (const float*)d_in[11];
  const float* ln_g = (const float*)d_in[12];
  const float* ln_b = (const float*)d_in[13];
  const float* W2 = (const float*)d_in[14];
  const float* b2 = (const float*)d_in[15];

  int N = in_sizes[0] / HDIM;
  int E = in_sizes[1] / 2;
  const int* srcp = edge_index;
  const int* dstp = edge_index + E;

  char* ws = (char*)d_ws;
  size_t off = 0;
  auto alloc = [&](size_t bytes) {
    char* p = ws + off;
    off = (off + bytes + 255) & ~(size_t)255;
    return p;
  };
  int* deg = (int*)alloc((size_t)N * 4);
  int* rowstart = (int*)alloc(((size_t)N + 1) * 4);
  int* fillptr = (int*)alloc((size_t)N * 4);
  float* bnsums = (float*)alloc(512);
  int* csr_src = (int*)alloc((size_t)E * 4);
  float* ea_csr = (float*)alloc((size_t)E * EDIM * 4);
  float* h = (float*)alloc((size_t)N * 64 * 4);
  float* hn = (float*)alloc((size_t)N * 64 * 4);
  float* outv = (float*)alloc((size_t)N * 64 * 4);
  (void)ws_size; (void)n_in; (void)out_size;

  hipMemsetAsync(deg, 0, (size_t)N * 4, stream);
  init_h_kernel<<<(N * 64 + 255) / 256, 256, 0, stream>>>(x, node_W, node_b, h, N);
  deg_kernel<<<(E + 255) / 256, 256, 0, stream>>>(dstp, deg, E);
  scan_kernel<<<1, 1024, 0, stream>>>(deg, rowstart, fillptr, N, E);
  fill_kernel<<<(E + 255) / 256, 256, 0, stream>>>(srcp, dstp, edge_attr, fillptr, csr_src, ea_csr, E);

  for (int l = 0; l < 3; ++l) {
    hipMemsetAsync(bnsums, 0, 512, stream);
    bn_stats_kernel<<<256, 256, 0, stream>>>(h, bnsums, N);
    normalize_kernel<<<(N * 64 + 255) / 256, 256, 0, stream>>>(h, bnsums, bn_g + l * 64, bn_b + l * 64,
                                                               hn, N, 1.0f / (float)N);
    aggregate_kernel<<<(N + 3) / 4, 256, 0, stream>>>(hn, rowstart, csr_src, ea_csr, edge_W, edge_b,
                                                      t + l, outv, N);
    float* hout = (l == 2) ? (float*)d_out : h;
    mlp_kernel<<<1563, 512, 0, stream>>>(outv, h, W1 + (size_t)l * 64 * 128, b1 + l * 128,
                                         ln_g + l * 128, ln_b + l * 128, W2 + (size_t)l * 128 * 64,
                                         b2 + l * 64, hout, N);
  }
}